// Round 1
// baseline (449.550 us; speedup 1.0000x reference)
//
#include <hip/hip_runtime.h>

// Dense image warp (bilinear), tfa.dense_image_warp semantics.
// image: (N,H,W,C) fp32, flow: (N,H,W,2) fp32, out: (N,H,W,C) fp32
// N=8, H=512, W=512, C=32.
//
// This version vs. 437us baseline:
//  - XCD-aware bijective block swizzle: 32768 blocks -> 8 contiguous chunks of
//    4096; each XCD processes exactly one batch image (32 MiB) so gathered
//    rows live in ONE private L2 instead of being duplicated across 8.
//  - Nontemporal output stores: don't evict the (exactly-L3-sized, 256 MiB)
//    image from Infinity Cache with the 256 MiB output stream.
//  - 2 pixels per thread (p, p+32 within a 64-pixel block group): halves wave
//    count, 8 corner gathers in flight per thread, index math amortized.
//    Stores stay perfectly coalesced (1024 B per wave per store).

typedef float f4 __attribute__((ext_vector_type(4)));

#define C4_CH 8  // C/4 = 32/4

__global__ __launch_bounds__(256) void dense_warp_kernel(
    const float* __restrict__ image,
    const float* __restrict__ flow,
    float* __restrict__ out) {
  const int H = 512, W = 512;

  // Bijective XCD swizzle: nwg = 32768 = 8 * 4096.
  int bid = blockIdx.x;
  int swz = (bid & 7) * 4096 + (bid >> 3);

  int t  = threadIdx.x;
  int c4 = t & (C4_CH - 1);  // float4-chunk within pixel
  int lp = t >> 3;           // local pixel 0..31

  int pixbase = swz << 6;    // 64 pixels per block
  int p0 = pixbase + lp;
  int p1 = p0 + 32;

  // flow: (pix, 2) -> [dy, dx]; 8 lanes share each float2 (L1 broadcast).
  const float2* fl2 = (const float2*)flow;
  float2 f0 = fl2[p0];
  float2 f1 = fl2[p1];

  int w0 = p0 & (W - 1);
  int h0 = (p0 >> 9) & (H - 1);
  int w1 = p1 & (W - 1);
  int h1 = (p1 >> 9) & (H - 1);
  int nb0 = (p0 >> 18) << 18;  // n * H*W   (H*W = 2^18)
  int nb1 = (p1 >> 18) << 18;

  float qy0 = (float)h0 - f0.x, qx0 = (float)w0 - f0.y;
  float qy1 = (float)h1 - f1.x, qx1 = (float)w1 - f1.y;

  float fy0f = fminf(fmaxf(floorf(qy0), 0.0f), (float)(H - 2));
  float fx0f = fminf(fmaxf(floorf(qx0), 0.0f), (float)(W - 2));
  float fy1f = fminf(fmaxf(floorf(qy1), 0.0f), (float)(H - 2));
  float fx1f = fminf(fmaxf(floorf(qx1), 0.0f), (float)(W - 2));
  float ay0 = fminf(fmaxf(qy0 - fy0f, 0.0f), 1.0f);
  float ax0 = fminf(fmaxf(qx0 - fx0f, 0.0f), 1.0f);
  float ay1 = fminf(fmaxf(qy1 - fy1f, 0.0f), 1.0f);
  float ax1 = fminf(fmaxf(qx1 - fx1f, 0.0f), 1.0f);
  int fy0 = (int)fy0f, fx0 = (int)fx0f;
  int fy1 = (int)fy1f, fx1 = (int)fx1f;

  // image as float4: ((n*H + y)*W + x)*8 + c4
  const f4* img4 = (const f4*)image;
  int i0 = ((nb0 + fy0 * W + fx0) << 3) + c4;
  int i1 = ((nb1 + fy1 * W + fx1) << 3) + c4;
  const int rowstep = W << 3;  // fy+1

  // Issue all 8 gathers back-to-back (independent -> deep MLP).
  f4 tl0 = img4[i0];
  f4 tr0 = img4[i0 + C4_CH];
  f4 bl0 = img4[i0 + rowstep];
  f4 br0 = img4[i0 + rowstep + C4_CH];
  f4 tl1 = img4[i1];
  f4 tr1 = img4[i1 + C4_CH];
  f4 bl1 = img4[i1 + rowstep];
  f4 br1 = img4[i1 + rowstep + C4_CH];

  f4 top0 = tl0 + ax0 * (tr0 - tl0);
  f4 bot0 = bl0 + ax0 * (br0 - bl0);
  f4 r0   = top0 + ay0 * (bot0 - top0);

  f4 top1 = tl1 + ax1 * (tr1 - tl1);
  f4 bot1 = bl1 + ax1 * (br1 - bl1);
  f4 r1   = top1 + ay1 * (bot1 - top1);

  // Nontemporal: keep L3 for the image.
  f4* out4 = (f4*)out;
  __builtin_nontemporal_store(r0, &out4[(p0 << 3) + c4]);
  __builtin_nontemporal_store(r1, &out4[(p1 << 3) + c4]);
}

extern "C" void kernel_launch(void* const* d_in, const int* in_sizes, int n_in,
                              void* d_out, int out_size, void* d_ws, size_t ws_size,
                              hipStream_t stream) {
  const float* image = (const float*)d_in[0];
  const float* flow  = (const float*)d_in[1];
  float* out = (float*)d_out;

  // 8*512*512 pixels / 64 pixels-per-block = 32768 blocks.
  dense_warp_kernel<<<32768, 256, 0, stream>>>(image, flow, out);
}

// Round 2
// 441.107 us; speedup vs baseline: 1.0191x; 1.0191x over previous
//
#include <hip/hip_runtime.h>

// Dense image warp (bilinear), tfa.dense_image_warp semantics.
// image: (N,H,W,C) fp32, flow: (N,H,W,2) fp32, out: (N,H,W,C) fp32
// N=8, H=512, W=512, C=32.
//
// Round 2: latency/miss-bound per counters (30% HBM, 11% VALU, 58% occ).
// Structural change: 2D 8x8 pixel tiles per block instead of 1x64 strips.
//  - 1x64 strip: ~300 unique 128B granules vs 256 accesses -> ~0% L1 reuse.
//  - 8x8 tile:   ~144 unique granules vs 256 accesses      -> ~45% L1 hits.
//  - Each thread does rows (r, r+1) of the same column -> intra-thread
//    granule overlap (guaranteed L1 hits).
//  - Kept: bijective XCD swizzle (one image per XCD; resident band ~2MB
//    fits 4MiB private L2), NT stores (protect L3-resident image), 8
//    independent gathers in flight per thread.

typedef float f4 __attribute__((ext_vector_type(4)));

#define C4_CH 8  // C/4

__global__ __launch_bounds__(256) void dense_warp_kernel(
    const float* __restrict__ image,
    const float* __restrict__ flow,
    float* __restrict__ out) {
  const int H = 512, W = 512;

  // grid: 32768 = 8 images * 64*64 tiles of 8x8 px.
  // Bijective XCD swizzle: 8 chunks of 4096 -> one image per XCD.
  int bid = blockIdx.x;
  int swz = (bid & 7) * 4096 + (bid >> 3);
  int n   = swz >> 12;        // image index
  int ti  = swz & 4095;       // tile within image
  int h0  = (ti >> 6) << 3;   // tile_row * 8
  int w0  = (ti & 63) << 3;   // tile_col * 8

  int t    = threadIdx.x;
  int c4   = t & (C4_CH - 1); // float4-chunk within pixel
  int slot = t >> 3;          // 0..31
  int col  = slot & 7;        // 0..7 within tile row
  int row2 = (slot >> 3) << 1; // 0,2,4,6: this thread does rows row2, row2+1

  int h_a = h0 + row2;
  int w   = w0 + col;

  int nHW = n << 18;                 // n * H*W
  int p0 = nHW + (h_a << 9) + w;     // pixel (n, h_a,   w)
  int p1 = p0 + W;                   // pixel (n, h_a+1, w)

  // flow: (pix, 2) -> [dy, dx]; 8 lanes of a pixel share one float2.
  const float2* fl2 = (const float2*)flow;
  float2 f0 = fl2[p0];
  float2 f1 = fl2[p1];

  float qy0 = (float)h_a       - f0.x, qx0 = (float)w - f0.y;
  float qy1 = (float)(h_a + 1) - f1.x, qx1 = (float)w - f1.y;

  float fy0f = fminf(fmaxf(floorf(qy0), 0.0f), (float)(H - 2));
  float fx0f = fminf(fmaxf(floorf(qx0), 0.0f), (float)(W - 2));
  float fy1f = fminf(fmaxf(floorf(qy1), 0.0f), (float)(H - 2));
  float fx1f = fminf(fmaxf(floorf(qx1), 0.0f), (float)(W - 2));
  float ay0 = fminf(fmaxf(qy0 - fy0f, 0.0f), 1.0f);
  float ax0 = fminf(fmaxf(qx0 - fx0f, 0.0f), 1.0f);
  float ay1 = fminf(fmaxf(qy1 - fy1f, 0.0f), 1.0f);
  float ax1 = fminf(fmaxf(qx1 - fx1f, 0.0f), 1.0f);
  int fy0 = (int)fy0f, fx0 = (int)fx0f;
  int fy1 = (int)fy1f, fx1 = (int)fx1f;

  // image as float4: ((n*H + y)*W + x)*8 + c4
  const f4* img4 = (const f4*)image;
  int i0 = ((nHW + fy0 * W + fx0) << 3) + c4;
  int i1 = ((nHW + fy1 * W + fx1) << 3) + c4;
  const int rowstep = W << 3;

  // 8 independent gathers in flight.
  f4 tl0 = img4[i0];
  f4 tr0 = img4[i0 + C4_CH];
  f4 bl0 = img4[i0 + rowstep];
  f4 br0 = img4[i0 + rowstep + C4_CH];
  f4 tl1 = img4[i1];
  f4 tr1 = img4[i1 + C4_CH];
  f4 bl1 = img4[i1 + rowstep];
  f4 br1 = img4[i1 + rowstep + C4_CH];

  f4 top0 = tl0 + ax0 * (tr0 - tl0);
  f4 bot0 = bl0 + ax0 * (br0 - bl0);
  f4 r0   = top0 + ay0 * (bot0 - top0);

  f4 top1 = tl1 + ax1 * (tr1 - tl1);
  f4 bot1 = bl1 + ax1 * (br1 - bl1);
  f4 r1   = top1 + ay1 * (bot1 - top1);

  // NT stores: keep the (exactly L3-sized) image resident in Infinity Cache.
  // Each wave writes two contiguous 1KB rows -> fully coalesced.
  f4* out4 = (f4*)out;
  __builtin_nontemporal_store(r0, &out4[(p0 << 3) + c4]);
  __builtin_nontemporal_store(r1, &out4[(p1 << 3) + c4]);
}

extern "C" void kernel_launch(void* const* d_in, const int* in_sizes, int n_in,
                              void* d_out, int out_size, void* d_ws, size_t ws_size,
                              hipStream_t stream) {
  const float* image = (const float*)d_in[0];
  const float* flow  = (const float*)d_in[1];
  float* out = (float*)d_out;

  // 8 images * (512/8)*(512/8) tiles = 32768 blocks.
  dense_warp_kernel<<<32768, 256, 0, stream>>>(image, flow, out);
}